// Round 5
// baseline (107.838 us; speedup 1.0000x reference)
//
#include <hip/hip_runtime.h>
#include <hip/hip_cooperative_groups.h>
#include <math.h>

namespace cg = cooperative_groups;

// B=128, N=512, D=1024, C=512
// s: (128,1536) f32, a=s[:,:512], z=s[:,512:]; out: (128,1536) f32 = [da | dz]
// GEMM1: da = tanh([a|ctx](128x1024) @ [Wa;Wc](1024x512) + ba)
// GEMM2: c  = a(128x512) @ Wl(512x1024) + bl          -> ws
// dz[b,i] = sum_k c[b,k] * z[b,(i+k)%1024]
//
// SINGLE cooperative kernel, 256 blocks x 512 threads:
//   phase 1 (blocks 0..191): GEMM jobs. job = 64 rows x 16 cols, 8 waves =
//     4 M-frags x 2 K-halves; B frags staged in LDS; A bf16-packed from
//     global; K-pair LDS reduce; direct epilogue (tanh / +bl).
//     jobs 0..63 = GEMM1 (mt=j>>5, nt=j&31); 64..191 = GEMM2 (mt,nt of Wl).
//   grid.sync()
//   phase 2 (all 256 blocks): dz, job = (batch, i-half)  [round-3 validated]
//
// Fragment k-slot bijection sigma(kq,j): j<4 -> 4kq+j ; j>=4 -> 16+4kq+(j-4),
// applied identically to A and B (validated rounds 2-4).

typedef float f32x4 __attribute__((ext_vector_type(4)));
typedef __bf16 bf16x8 __attribute__((ext_vector_type(8)));

__device__ __forceinline__ bf16x8 pack2(float4 v0, float4 v1) {
    bf16x8 r;
    r[0] = (__bf16)v0.x; r[1] = (__bf16)v0.y; r[2] = (__bf16)v0.z; r[3] = (__bf16)v0.w;
    r[4] = (__bf16)v1.x; r[5] = (__bf16)v1.y; r[6] = (__bf16)v1.z; r[7] = (__bf16)v1.w;
    return r;
}

__device__ __forceinline__ f32x4 MFMA(bf16x8 a, uint4 b, f32x4 c) {
    return __builtin_amdgcn_mfma_f32_16x16x32_bf16(a, __builtin_bit_cast(bf16x8, b), c, 0, 0, 0);
}

__global__ __launch_bounds__(512) void k_fused(
    const float* __restrict__ s, const float* __restrict__ ctx,
    const float* __restrict__ Wa, const float* __restrict__ Wc,
    const float* __restrict__ ba, const float* __restrict__ Wl,
    const float* __restrict__ bl, float* __restrict__ out,
    float* __restrict__ cws)
{
    // phase1: Bg frags [<=32 ks][64 l][8 bf16] = 32 KB @0 ; red [4][16][20] f32 @32768
    // phase2: zdup 2064 f @0 ; part 8*512 f @8448
    __shared__ __align__(16) unsigned char smem[37888];

    const int bid = blockIdx.x;
    const int t = threadIdx.x;
    const int w = t >> 6, l = t & 63;
    const int lk = l & 15, kq = l >> 4;

    // ======================= phase 1: both GEMMs =======================
    if (bid < 192) {
        const bool g1 = bid < 64;
        int mt, nt, KS, ldw;
        if (g1) { mt = bid >> 5; nt = bid & 31; KS = 32; ldw = 512; }
        else { const int j = bid - 64; mt = j >> 6; nt = j & 63; KS = 16; ldw = 1024; }
        unsigned short* Bg = reinterpret_cast<unsigned short*>(smem);
        const int col = nt * 16 + lk;

        // ---- stage B frags (each wave stages KS/8 ks)
        const int nstg = KS >> 3;
        #pragma unroll 4
        for (int i = 0; i < nstg; ++i) {
            const int ks = w * nstg + i;
            const int kb = ks * 32;
            const float* wb; int krel;
            if (g1) { if (ks < 16) { wb = Wa; krel = kb; } else { wb = Wc; krel = kb - 512; } }
            else    { wb = Wl; krel = kb; }
            bf16x8 fr;
            #pragma unroll
            for (int jj = 0; jj < 4; ++jj)
                fr[jj] = (__bf16)wb[(size_t)(krel + 4 * kq + jj) * ldw + col];
            #pragma unroll
            for (int jj = 0; jj < 4; ++jj)
                fr[4 + jj] = (__bf16)wb[(size_t)(krel + 16 + 4 * kq + jj) * ldw + col];
            *reinterpret_cast<uint4*>(&Bg[(ks * 64 + l) * 8]) = __builtin_bit_cast(uint4, fr);
        }
        __syncthreads();

        // ---- compute: wave = (wm M-frag, wk K-half); rows R0..R0+15, full tile cols
        const int wm = w & 3, wk = w >> 2;
        const int R0 = mt * 64 + wm * 16;
        const float* srow = s + (size_t)(R0 + lk) * 1536;
        const float* crow = ctx + (size_t)(R0 + lk) * 512;
        const int KH = KS >> 1;
        f32x4 acc0 = (f32x4){0.f, 0.f, 0.f, 0.f};
        f32x4 acc1 = (f32x4){0.f, 0.f, 0.f, 0.f};
        #pragma unroll 4
        for (int i = 0; i < KH; ++i) {
            const int ks = wk * KH + i;
            const int kb = ks * 32;
            float4 v0, v1;
            if (g1 && ks >= 16) {
                v0 = *reinterpret_cast<const float4*>(crow + (kb - 512) + 4 * kq);
                v1 = *reinterpret_cast<const float4*>(crow + (kb - 512) + 16 + 4 * kq);
            } else {
                v0 = *reinterpret_cast<const float4*>(srow + kb + 4 * kq);
                v1 = *reinterpret_cast<const float4*>(srow + kb + 16 + 4 * kq);
            }
            bf16x8 af = pack2(v0, v1);
            uint4 bv = *reinterpret_cast<const uint4*>(&Bg[(ks * 64 + l) * 8]);
            if (i & 1) acc1 = MFMA(af, bv, acc1);
            else       acc0 = MFMA(af, bv, acc0);
        }
        f32x4 sum = acc0 + acc1;

        // ---- K-pair reduce (wk=1 -> LDS, wk=0 adds + epilogue)
        float* red = reinterpret_cast<float*>(smem + 32768);   // [4][16][20]
        if (wk == 1) {
            #pragma unroll
            for (int r = 0; r < 4; ++r)
                red[(wm * 16 + 4 * kq + r) * 20 + lk] = sum[r];
        }
        __syncthreads();
        if (wk == 0) {
            if (g1) {
                const float bias = ba[col];
                #pragma unroll
                for (int r = 0; r < 4; ++r) {
                    float v = sum[r] + red[(wm * 16 + 4 * kq + r) * 20 + lk] + bias;
                    out[(size_t)(R0 + 4 * kq + r) * 1536 + col] = tanhf(v);
                }
            } else {
                const float bias = bl[col];
                #pragma unroll
                for (int r = 0; r < 4; ++r) {
                    float v = sum[r] + red[(wm * 16 + 4 * kq + r) * 20 + lk] + bias;
                    cws[(size_t)(R0 + 4 * kq + r) * 1024 + col] = v;
                }
            }
        }
    }

    __threadfence();
    cg::this_grid().sync();

    // ======================= phase 2: dz =======================
    {
        float* zdup = reinterpret_cast<float*>(smem);                 // 2064 f
        float* part = reinterpret_cast<float*>(smem + 8448);          // 8*512 f
        const int b = bid >> 1;
        const int ih = bid & 1;
        if (t < 256) {
            float4 v = reinterpret_cast<const float4*>(s + (size_t)b * 1536 + 512)[t];
            reinterpret_cast<float4*>(zdup)[t] = v;
            reinterpret_cast<float4*>(zdup)[256 + t] = v;
        }
        __syncthreads();
        const int g = t & 63;
        const int kq2 = __builtin_amdgcn_readfirstlane(t >> 6);
        const float4* c4 = reinterpret_cast<const float4*>(cws + (size_t)b * 1024 + kq2 * 128);
        const int I0 = ih * 512;
        const float4* z4 = reinterpret_cast<const float4*>(zdup);
        const int baseA = (I0 >> 2) + g + kq2 * 32;
        const int baseB = baseA + 64;
        float4 a0 = z4[baseA], a1 = z4[baseA + 1];
        float4 b0 = z4[baseB], b1 = z4[baseB + 1];
        float accA[4] = {0.f, 0.f, 0.f, 0.f}, accB[4] = {0.f, 0.f, 0.f, 0.f};
        #pragma unroll 4
        for (int m = 0; m < 32; ++m) {
            float4 cv = c4[m];
            float4 a2 = z4[baseA + m + 2];
            float4 b2 = z4[baseB + m + 2];
            accA[0] = fmaf(cv.x, a0.x, accA[0]); accA[0] = fmaf(cv.y, a0.y, accA[0]);
            accA[0] = fmaf(cv.z, a0.z, accA[0]); accA[0] = fmaf(cv.w, a0.w, accA[0]);
            accA[1] = fmaf(cv.x, a0.y, accA[1]); accA[1] = fmaf(cv.y, a0.z, accA[1]);
            accA[1] = fmaf(cv.z, a0.w, accA[1]); accA[1] = fmaf(cv.w, a1.x, accA[1]);
            accA[2] = fmaf(cv.x, a0.z, accA[2]); accA[2] = fmaf(cv.y, a0.w, accA[2]);
            accA[2] = fmaf(cv.z, a1.x, accA[2]); accA[2] = fmaf(cv.w, a1.y, accA[2]);
            accA[3] = fmaf(cv.x, a0.w, accA[3]); accA[3] = fmaf(cv.y, a1.x, accA[3]);
            accA[3] = fmaf(cv.z, a1.y, accA[3]); accA[3] = fmaf(cv.w, a1.z, accA[3]);
            accB[0] = fmaf(cv.x, b0.x, accB[0]); accB[0] = fmaf(cv.y, b0.y, accB[0]);
            accB[0] = fmaf(cv.z, b0.z, accB[0]); accB[0] = fmaf(cv.w, b0.w, accB[0]);
            accB[1] = fmaf(cv.x, b0.y, accB[1]); accB[1] = fmaf(cv.y, b0.z, accB[1]);
            accB[1] = fmaf(cv.z, b0.w, accB[1]); accB[1] = fmaf(cv.w, b1.x, accB[1]);
            accB[2] = fmaf(cv.x, b0.z, accB[2]); accB[2] = fmaf(cv.y, b0.w, accB[2]);
            accB[2] = fmaf(cv.z, b1.x, accB[2]); accB[2] = fmaf(cv.w, b1.y, accB[2]);
            accB[3] = fmaf(cv.x, b0.w, accB[3]); accB[3] = fmaf(cv.y, b1.x, accB[3]);
            accB[3] = fmaf(cv.z, b1.y, accB[3]); accB[3] = fmaf(cv.w, b1.z, accB[3]);
            a0 = a1; a1 = a2; b0 = b1; b1 = b2;
        }
        *reinterpret_cast<float4*>(&part[kq2 * 512 + 4 * g]) = make_float4(accA[0], accA[1], accA[2], accA[3]);
        *reinterpret_cast<float4*>(&part[kq2 * 512 + 256 + 4 * g]) = make_float4(accB[0], accB[1], accB[2], accB[3]);
        __syncthreads();
        float sumz = 0.f;
        #pragma unroll
        for (int q = 0; q < 8; ++q) sumz += part[q * 512 + t];
        out[(size_t)b * 1536 + 512 + I0 + t] = sumz;
    }
}

extern "C" void kernel_launch(void* const* d_in, const int* in_sizes, int n_in,
                              void* d_out, int out_size, void* d_ws, size_t ws_size,
                              hipStream_t stream) {
    // inputs: 0=t, 1=s, 2=context, 3=Wa, 4=Wc, 5=ba, 6=Wl, 7=bl
    const float* s   = (const float*)d_in[1];
    const float* ctx = (const float*)d_in[2];
    const float* Wa  = (const float*)d_in[3];
    const float* Wc  = (const float*)d_in[4];
    const float* ba  = (const float*)d_in[5];
    const float* Wl  = (const float*)d_in[6];
    const float* bl  = (const float*)d_in[7];
    float* out = (float*)d_out;
    float* cws = (float*)d_ws;

    void* args[] = {(void*)&s, (void*)&ctx, (void*)&Wa, (void*)&Wc, (void*)&ba,
                    (void*)&Wl, (void*)&bl, (void*)&out, (void*)&cws};
    hipLaunchCooperativeKernel(reinterpret_cast<void*>(k_fused),
                               dim3(256), dim3(512), args, 0, stream);
}

// Round 6
// 21.728 us; speedup vs baseline: 4.9631x; 4.9631x over previous
//
#include <hip/hip_runtime.h>
#include <math.h>

// B=128, N=512, D=1024, C=512
// s: (128,1536) f32, a=s[:,:512], z=s[:,512:]; out: (128,1536) f32 = [da | dz]
// GEMM1: da = tanh([a|ctx](128x1024) @ [Wa;Wc](1024x512) + ba)
// GEMM2: c  = a(128x512) @ Wl(512x1024) + bl          -> ws
// dz[b,i] = sum_k c[b,k] * z[b,(i+k)%1024]
//
// kG (192 blocks x 512): GEMM jobs. job = 64 rows x 16 cols, 8 waves =
//   4 M-frags x 2 K-halves; B frags staged in LDS directly from global;
//   A bf16-packed on the fly; K-pair LDS reduce; direct epilogue.
//   jobs 0..63 = GEMM1; 64..191 = GEMM2.   [code validated in round 5]
// kZ (256 blocks x 512): dz, job = (batch, i-half).  [validated round 3]
//
// Fragment k-slot bijection sigma(kq,j): j<4 -> 4kq+j ; j>=4 -> 16+4kq+(j-4),
// applied identically to A and B (validated rounds 2-5).

typedef float f32x4 __attribute__((ext_vector_type(4)));
typedef __bf16 bf16x8 __attribute__((ext_vector_type(8)));

__device__ __forceinline__ bf16x8 pack2(float4 v0, float4 v1) {
    bf16x8 r;
    r[0] = (__bf16)v0.x; r[1] = (__bf16)v0.y; r[2] = (__bf16)v0.z; r[3] = (__bf16)v0.w;
    r[4] = (__bf16)v1.x; r[5] = (__bf16)v1.y; r[6] = (__bf16)v1.z; r[7] = (__bf16)v1.w;
    return r;
}

__device__ __forceinline__ f32x4 MFMA(bf16x8 a, uint4 b, f32x4 c) {
    return __builtin_amdgcn_mfma_f32_16x16x32_bf16(a, __builtin_bit_cast(bf16x8, b), c, 0, 0, 0);
}

// ---------------------------------------------------------------------------
// kG: 192 blocks x 512 threads — both GEMMs, no workspace inputs.
// ---------------------------------------------------------------------------
__global__ __launch_bounds__(512) void kG(
    const float* __restrict__ s, const float* __restrict__ ctx,
    const float* __restrict__ Wa, const float* __restrict__ Wc,
    const float* __restrict__ ba, const float* __restrict__ Wl,
    const float* __restrict__ bl, float* __restrict__ out,
    float* __restrict__ cws)
{
    // Bg frags [<=32 ks][64 l][8 bf16] = 32 KB @0 ; red [4][16][20] f32 @32768
    __shared__ __align__(16) unsigned char smem[37888];

    const int bid = blockIdx.x;
    const int t = threadIdx.x;
    const int w = t >> 6, l = t & 63;
    const int lk = l & 15, kq = l >> 4;

    const bool g1 = bid < 64;
    int mt, nt, KS, ldw;
    if (g1) { mt = bid >> 5; nt = bid & 31; KS = 32; ldw = 512; }
    else { const int j = bid - 64; mt = j >> 6; nt = j & 63; KS = 16; ldw = 1024; }
    unsigned short* Bg = reinterpret_cast<unsigned short*>(smem);
    const int col = nt * 16 + lk;

    // ---- stage B frags (each wave stages KS/8 ks)
    const int nstg = KS >> 3;
    #pragma unroll 4
    for (int i = 0; i < nstg; ++i) {
        const int ks = w * nstg + i;
        const int kb = ks * 32;
        const float* wb; int krel;
        if (g1) { if (ks < 16) { wb = Wa; krel = kb; } else { wb = Wc; krel = kb - 512; } }
        else    { wb = Wl; krel = kb; }
        bf16x8 fr;
        #pragma unroll
        for (int jj = 0; jj < 4; ++jj)
            fr[jj] = (__bf16)wb[(size_t)(krel + 4 * kq + jj) * ldw + col];
        #pragma unroll
        for (int jj = 0; jj < 4; ++jj)
            fr[4 + jj] = (__bf16)wb[(size_t)(krel + 16 + 4 * kq + jj) * ldw + col];
        *reinterpret_cast<uint4*>(&Bg[(ks * 64 + l) * 8]) = __builtin_bit_cast(uint4, fr);
    }
    __syncthreads();

    // ---- compute: wave = (wm M-frag, wk K-half); rows R0..R0+15
    const int wm = w & 3, wk = w >> 2;
    const int R0 = mt * 64 + wm * 16;
    const float* srow = s + (size_t)(R0 + lk) * 1536;
    const float* crow = ctx + (size_t)(R0 + lk) * 512;
    const int KH = KS >> 1;
    f32x4 acc0 = (f32x4){0.f, 0.f, 0.f, 0.f};
    f32x4 acc1 = (f32x4){0.f, 0.f, 0.f, 0.f};
    #pragma unroll 4
    for (int i = 0; i < KH; ++i) {
        const int ks = wk * KH + i;
        const int kb = ks * 32;
        float4 v0, v1;
        if (g1 && ks >= 16) {
            v0 = *reinterpret_cast<const float4*>(crow + (kb - 512) + 4 * kq);
            v1 = *reinterpret_cast<const float4*>(crow + (kb - 512) + 16 + 4 * kq);
        } else {
            v0 = *reinterpret_cast<const float4*>(srow + kb + 4 * kq);
            v1 = *reinterpret_cast<const float4*>(srow + kb + 16 + 4 * kq);
        }
        bf16x8 af = pack2(v0, v1);
        uint4 bv = *reinterpret_cast<const uint4*>(&Bg[(ks * 64 + l) * 8]);
        if (i & 1) acc1 = MFMA(af, bv, acc1);
        else       acc0 = MFMA(af, bv, acc0);
    }
    f32x4 sum = acc0 + acc1;

    // ---- K-pair reduce (wk=1 -> LDS, wk=0 adds + epilogue)
    float* red = reinterpret_cast<float*>(smem + 32768);   // [4][16][20]
    if (wk == 1) {
        #pragma unroll
        for (int r = 0; r < 4; ++r)
            red[(wm * 16 + 4 * kq + r) * 20 + lk] = sum[r];
    }
    __syncthreads();
    if (wk == 0) {
        if (g1) {
            const float bias = ba[col];
            #pragma unroll
            for (int r = 0; r < 4; ++r) {
                float v = sum[r] + red[(wm * 16 + 4 * kq + r) * 20 + lk] + bias;
                out[(size_t)(R0 + 4 * kq + r) * 1536 + col] = tanhf(v);
            }
        } else {
            const float bias = bl[col];
            #pragma unroll
            for (int r = 0; r < 4; ++r) {
                float v = sum[r] + red[(wm * 16 + 4 * kq + r) * 20 + lk] + bias;
                cws[(size_t)(R0 + 4 * kq + r) * 1024 + col] = v;
            }
        }
    }
}

// ---------------------------------------------------------------------------
// kZ: 256 blocks x 512 threads — dz (fp32 VALU rolling-window circular corr).
// ---------------------------------------------------------------------------
__global__ __launch_bounds__(512) void kZ(const float* __restrict__ s,
                                          const float* __restrict__ cws,
                                          float* __restrict__ out)
{
    __shared__ __align__(16) float zdup[2064];
    __shared__ float part[8 * 512];
    const int b = blockIdx.x >> 1;
    const int ih = blockIdx.x & 1;
    const int t = threadIdx.x;
    if (t < 256) {
        float4 v = reinterpret_cast<const float4*>(s + (size_t)b * 1536 + 512)[t];
        reinterpret_cast<float4*>(zdup)[t] = v;
        reinterpret_cast<float4*>(zdup)[256 + t] = v;
    }
    __syncthreads();
    const int g = t & 63;
    const int kq = __builtin_amdgcn_readfirstlane(t >> 6);
    const float4* c4 = reinterpret_cast<const float4*>(cws + (size_t)b * 1024 + kq * 128);
    const int I0 = ih * 512;
    const float4* z4 = reinterpret_cast<const float4*>(zdup);
    const int baseA = (I0 >> 2) + g + kq * 32;
    const int baseB = baseA + 64;
    float4 a0 = z4[baseA], a1 = z4[baseA + 1];
    float4 b0 = z4[baseB], b1 = z4[baseB + 1];
    float accA[4] = {0.f, 0.f, 0.f, 0.f}, accB[4] = {0.f, 0.f, 0.f, 0.f};
    #pragma unroll 4
    for (int m = 0; m < 32; ++m) {
        float4 cv = c4[m];
        float4 a2 = z4[baseA + m + 2];
        float4 b2 = z4[baseB + m + 2];
        accA[0] = fmaf(cv.x, a0.x, accA[0]); accA[0] = fmaf(cv.y, a0.y, accA[0]);
        accA[0] = fmaf(cv.z, a0.z, accA[0]); accA[0] = fmaf(cv.w, a0.w, accA[0]);
        accA[1] = fmaf(cv.x, a0.y, accA[1]); accA[1] = fmaf(cv.y, a0.z, accA[1]);
        accA[1] = fmaf(cv.z, a0.w, accA[1]); accA[1] = fmaf(cv.w, a1.x, accA[1]);
        accA[2] = fmaf(cv.x, a0.z, accA[2]); accA[2] = fmaf(cv.y, a0.w, accA[2]);
        accA[2] = fmaf(cv.z, a1.x, accA[2]); accA[2] = fmaf(cv.w, a1.y, accA[2]);
        accA[3] = fmaf(cv.x, a0.w, accA[3]); accA[3] = fmaf(cv.y, a1.x, accA[3]);
        accA[3] = fmaf(cv.z, a1.y, accA[3]); accA[3] = fmaf(cv.w, a1.z, accA[3]);
        accB[0] = fmaf(cv.x, b0.x, accB[0]); accB[0] = fmaf(cv.y, b0.y, accB[0]);
        accB[0] = fmaf(cv.z, b0.z, accB[0]); accB[0] = fmaf(cv.w, b0.w, accB[0]);
        accB[1] = fmaf(cv.x, b0.y, accB[1]); accB[1] = fmaf(cv.y, b0.z, accB[1]);
        accB[1] = fmaf(cv.z, b0.w, accB[1]); accB[1] = fmaf(cv.w, b1.x, accB[1]);
        accB[2] = fmaf(cv.x, b0.z, accB[2]); accB[2] = fmaf(cv.y, b0.w, accB[2]);
        accB[2] = fmaf(cv.z, b1.x, accB[2]); accB[2] = fmaf(cv.w, b1.y, accB[2]);
        accB[3] = fmaf(cv.x, b0.w, accB[3]); accB[3] = fmaf(cv.y, b1.x, accB[3]);
        accB[3] = fmaf(cv.z, b1.y, accB[3]); accB[3] = fmaf(cv.w, b1.z, accB[3]);
        a0 = a1; a1 = a2; b0 = b1; b1 = b2;
    }
    *reinterpret_cast<float4*>(&part[kq * 512 + 4 * g]) = make_float4(accA[0], accA[1], accA[2], accA[3]);
    *reinterpret_cast<float4*>(&part[kq * 512 + 256 + 4 * g]) = make_float4(accB[0], accB[1], accB[2], accB[3]);
    __syncthreads();
    float sum = 0.f;
    #pragma unroll
    for (int q = 0; q < 8; ++q) sum += part[q * 512 + t];
    out[(size_t)b * 1536 + 512 + I0 + t] = sum;
}

extern "C" void kernel_launch(void* const* d_in, const int* in_sizes, int n_in,
                              void* d_out, int out_size, void* d_ws, size_t ws_size,
                              hipStream_t stream) {
    // inputs: 0=t, 1=s, 2=context, 3=Wa, 4=Wc, 5=ba, 6=Wl, 7=bl
    const float* s   = (const float*)d_in[1];
    const float* ctx = (const float*)d_in[2];
    const float* Wa  = (const float*)d_in[3];
    const float* Wc  = (const float*)d_in[4];
    const float* ba  = (const float*)d_in[5];
    const float* Wl  = (const float*)d_in[6];
    const float* bl  = (const float*)d_in[7];
    float* out = (float*)d_out;
    float* cws = (float*)d_ws;

    kG<<<192, 512, 0, stream>>>(s, ctx, Wa, Wc, ba, Wl, bl, out, cws);
    kZ<<<256, 512, 0, stream>>>(s, cws, out);
}